// Round 15
// baseline (462.492 us; speedup 1.0000x reference)
//
#include <hip/hip_runtime.h>
#include <hip/hip_bf16.h>
#include <stdint.h>

// AWQ GEMM: out[2048,11008](f32) = x[2048,4096](f32,f16-valued) @ dequant4(...) + bias
// Round 15: A never touches LDS.
//  K1: X f32 -> f16 into d_ws in MFMA-FRAGMENT order:
//      chunk(mt,kt,ks,wm,mi) = 1KB; lane l holds rows mt*256+wm*64+mi*16+(l&15),
//      k-octet kt*64 + (ks*4 + (l>>4))*8. A-fragment load = one coalesced
//      global_load_dwordx4 at base + lane*16, straight to VGPR.
//  K2: r14 body, minus all A LDS machinery: LDS = B double-buffer only (32 KB),
//      LDS traffic/iter 176KB -> 80KB, one barrier/iter, A-loads barrier-free.
// Fallback (ws too small): r12 single-kernel path.

constexpr int TOKENS = 2048;
constexpr int IN_F   = 4096;
constexpr int OUT_F  = 11008;
constexpr int PCOLS  = OUT_F / 8;   // 1376
constexpr int BM = 256, BN = 128, BK = 64;
constexpr int NKT    = IN_F / BK;   // 64
constexpr int NTILES = OUT_F / BN;  // 86
constexpr int BBYTES = BN * BK * 2; // 16384 per buffer
constexpr size_t XSW_BYTES = (size_t)TOKENS * IN_F * 2; // 16 MB

typedef _Float16 h2 __attribute__((ext_vector_type(2)));
typedef _Float16 h8 __attribute__((ext_vector_type(8)));
typedef float f32x4  __attribute__((ext_vector_type(4)));

__device__ __forceinline__ h2 pkh2(float a, float b) {
    return __builtin_bit_cast(h2, __builtin_amdgcn_cvt_pkrtz(a, b));
}
__device__ __forceinline__ unsigned int pk2(float a, float b) {
    return __builtin_bit_cast(unsigned int, __builtin_amdgcn_cvt_pkrtz(a, b));
}

// ---------------- K1: convert X into fragment-ordered f16 ----------------
__global__ __launch_bounds__(256)
void x_convert_kernel(const float* __restrict__ X, unsigned short* __restrict__ Xsw)
{
    // one thread per 16B fragment chunk:
    // g = ((((mt*64 + kt)*2 + ks)*4 + wm)*4 + mi)*64 + lane
    const int g    = blockIdx.x * 256 + threadIdx.x;   // 0 .. 2^20-1
    const int lane = g & 63;
    const int mi   = (g >> 6) & 3;
    const int wm   = (g >> 8) & 3;
    const int ks   = (g >> 10) & 1;
    const int kt   = (g >> 11) & 63;
    const int mt   = g >> 17;
    const int row  = mt * 256 + wm * 64 + mi * 16 + (lane & 15);
    const int kcol = kt * 64 + (ks * 4 + (lane >> 4)) * 8;
    const float* src = X + (size_t)row * IN_F + kcol;
    float4 v0 = *(const float4*)(src);
    float4 v1 = *(const float4*)(src + 4);
    uint4 u;
    u.x = pk2(v0.x, v0.y);
    u.y = pk2(v0.z, v0.w);
    u.z = pk2(v1.x, v1.y);
    u.w = pk2(v1.z, v1.w);
    *(uint4*)(Xsw + (size_t)g * 8) = u;
}

// ---------------- K2: main GEMM (A global->reg, B via LDS dequant) ----------------
__global__ __launch_bounds__(512, 2)
void awq_gemm_reg_kernel(const unsigned short* __restrict__ Xsw,
                         const int*   __restrict__ QW,
                         const int*   __restrict__ QZ,
                         const float* __restrict__ S,
                         const float* __restrict__ BIAS,
                         float*       __restrict__ O)
{
    // LDS: B buf b at b*16384: [128 cols][128B]; k-octet o of col n at slot o^(n&7)^((n>>3)&7)
    __shared__ alignas(16) unsigned char smem[2 * BBYTES];  // 32 KB

    const int t    = threadIdx.x;
    const int lane = t & 63;
    const int w    = t >> 6;      // 0..7
    const int wm   = w >> 1;      // 0..3 (row block of 64)
    const int wn   = w & 1;       // 0..1 (col block of 64)
    const int l15 = lane & 15, l45 = lane >> 4, l7 = lane & 7, l3 = (lane >> 3) & 1;

    // XCD mapping: XCD x (= bid&7) owns mtile x; sweeps all 86 ntiles. 688 = 8*86.
    const int bid   = blockIdx.x;
    const int mtile = bid & 7;
    const int ntile = bid >> 3;
    const int m0 = mtile * BM;
    const int n0 = ntile * BN;
    const int P0 = n0 >> 3;

    // ---- A fragments: direct global loads from fragment-ordered Xsw ----
    const h8* Afrag = (const h8*)Xsw;   // 16B units
    auto load_a = [&](h8 (&a)[4], int kt, int ks) {
        const size_t base = ((((size_t)mtile * 64 + kt) * 2 + ks) * 4 + wm) * 4;
#pragma unroll
        for (int mi = 0; mi < 4; ++mi)
            a[mi] = Afrag[(base + mi) * 64 + lane];
    };

    // ---- B staging: thread covers packed col pcol = t&15, k-pair 2kd, 2kd+1 (kd = t>>4) ----
    const int pcol = t & 15;
    const int kd   = t >> 4;         // 0..31
    const int pc7  = pcol & 7;
    const int ob   = kd >> 2;        // k-octet
    const int sub  = (kd & 3) * 4;   // byte offset within 16B slot
    const int* qwb = QW + (size_t)(2 * kd) * PCOLS + P0 + pcol;
    const unsigned int* qzc = (const unsigned int*)QZ + P0 + pcol;
    const float* scol = S + n0 + pcol * 8;

    constexpr int SH[8]  = {0, 16, 4, 20, 8, 24, 12, 28}; // shift of logical nibble j
    constexpr int JLO[4] = {0, 4, 1, 5};                  // low-nibble j of byte b

    h2 spk[8], zpk[8];
    unsigned int zraw_n; float4 sv0, sv1;
    unsigned int raw0, raw1;

    auto load_group = [&](int g) {
        zraw_n = qzc[(size_t)g * PCOLS];
        sv0 = *(const float4*)(scol + (size_t)g * OUT_F);
        sv1 = *(const float4*)(scol + (size_t)g * OUT_F + 4);
    };
    auto compute_group = [&]() {
        const float sf[8] = {sv0.x, sv0.y, sv0.z, sv0.w, sv1.x, sv1.y, sv1.z, sv1.w};
#pragma unroll
        for (int j = 0; j < 8; ++j) {
            float zb = 1024.0f + (float)((zraw_n >> SH[j]) & 15u);  // exact in f16
            spk[j] = pkh2(sf[j], sf[j]);
            zpk[j] = pkh2(zb, zb);
        }
    };
    auto load_raws = [&](int kt) {
        const size_t off = (size_t)kt * BK * PCOLS;
        raw0 = (unsigned int)qwb[off];
        raw1 = (unsigned int)qwb[off + PCOLS];
    };
    auto stage_B = [&](int buf) {
        unsigned char* bb = smem + buf * BBYTES;
#pragma unroll
        for (int b = 0; b < 4; ++b) {
            const int jl = JLO[b], jh = jl + 2;
            unsigned int d  = __builtin_amdgcn_perm(raw1, raw0,
                                 (unsigned int)(((4 + b) << 16) | b));
            unsigned int lo = (d & 0x000F000Fu) | 0x64006400u;         // (1024+q), j=jl
            unsigned int hi = ((d >> 4) & 0x000F000Fu) | 0x64006400u;  // j=jh
            h2 wl = (__builtin_bit_cast(h2, lo) - zpk[jl]) * spk[jl];  // exact sub, 1 rounding
            h2 wh = (__builtin_bit_cast(h2, hi) - zpk[jh]) * spk[jh];
            const int nl = pcol * 8 + jl, nh = pcol * 8 + jh;
            *(unsigned int*)(bb + nl * 128 + ((ob ^ jl ^ pc7) * 16) + sub) =
                __builtin_bit_cast(unsigned int, wl);
            *(unsigned int*)(bb + nh * 128 + ((ob ^ jh ^ pc7) * 16) + sub) =
                __builtin_bit_cast(unsigned int, wh);
        }
    };

    f32x4 acc[4][4];
#pragma unroll
    for (int mi = 0; mi < 4; ++mi)
#pragma unroll
        for (int ni = 0; ni < 4; ++ni)
            acc[mi][ni] = f32x4{0.f, 0.f, 0.f, 0.f};

    auto compute_tile = [&](int buf, int kt) {
        const unsigned char* bb = smem + buf * BBYTES;
#pragma unroll
        for (int ks = 0; ks < 2; ++ks) {
            h8 a[4], bf[4];
            load_a(a, kt, ks);                 // global->reg, coalesced 1KB/wave
#pragma unroll
            for (int ni = 0; ni < 4; ++ni) {
                int off = (wn * 64 + ni * 16 + l15) * 128
                        + ((((ks * 4 + l45) ^ l7 ^ l3) ^ (2 * ni)) * 16); // n&7==l7
                bf[ni] = *(const h8*)(bb + off);
            }
#pragma unroll
            for (int mi = 0; mi < 4; ++mi)
#pragma unroll
                for (int ni = 0; ni < 4; ++ni)
                    acc[mi][ni] = __builtin_amdgcn_mfma_f32_16x16x32_f16(
                        a[mi], bf[ni], acc[mi][ni], 0, 0, 0);
        }
    };

    // ---- prologue: stage B tile 0 into buf 0 ----
    load_raws(0);
    load_group(0);
    compute_group();
    stage_B(0);
    __syncthreads();

    // ---- main loop: ONE barrier per iter; A never in LDS ----
#pragma unroll 2
    for (int kt = 0; kt < NKT; ++kt) {
        const int cur = kt & 1;
        if (kt + 1 < NKT) {
            load_raws(kt + 1);                 // issue-early (T14)
            if (((kt + 1) & 1) == 0) load_group((kt + 1) >> 1);
        }
        compute_tile(cur, kt);
        if (kt + 1 < NKT) {
            if (((kt + 1) & 1) == 0) compute_group();
            stage_B(cur ^ 1);
        }
        __syncthreads();
    }

    // ---- epilogue: bias + f32 store (C/D: col=lane&15, row=(lane>>4)*4+reg) ----
    const int orow0 = m0 + wm * 64 + l45 * 4;
    const int ocol0 = n0 + wn * 64 + l15;
    float bv[4];
#pragma unroll
    for (int ni = 0; ni < 4; ++ni)
        bv[ni] = BIAS[ocol0 + ni * 16];
#pragma unroll
    for (int mi = 0; mi < 4; ++mi)
#pragma unroll
        for (int ni = 0; ni < 4; ++ni)
#pragma unroll
            for (int r = 0; r < 4; ++r) {
                int row = orow0 + mi * 16 + r;
                int col = ocol0 + ni * 16;
                O[(size_t)row * OUT_F + col] = acc[mi][ni][r] + bv[ni];
            }
}

// ---------------- fallback: r12 kernel (ws too small) ----------------
constexpr int ABYTES_FB = BM * BK * 2; // 32768

__global__ __launch_bounds__(512, 2)
void awq_gemm_fb_kernel(const float* __restrict__ X,
                        const int*   __restrict__ QW,
                        const int*   __restrict__ QZ,
                        const float* __restrict__ S,
                        const float* __restrict__ BIAS,
                        float*       __restrict__ O)
{
    __shared__ alignas(16) unsigned char smem[ABYTES_FB + 2 * BBYTES];

    const int t    = threadIdx.x;
    const int lane = t & 63;
    const int w    = t >> 6;
    const int wm   = w >> 1;
    const int wn   = w & 1;
    const int l15 = lane & 15, l45 = lane >> 4, l7 = lane & 7, l3 = (lane >> 3) & 1;

    const int bid   = blockIdx.x;
    const int mtile = bid & 7;
    const int ntile = bid >> 3;
    const int m0 = mtile * BM;
    const int n0 = ntile * BN;
    const int P0 = n0 >> 3;

    const int arow = t >> 3;
    const int aoct = t & 7;
    const int aphys = aoct ^ (arow & 7);
    const float* Xb = X + (size_t)(m0 + arow) * IN_F + aoct * 8;

    float4 areg[4][2];
    auto load_A = [&](int kt) {
#pragma unroll
        for (int i = 0; i < 4; ++i) {
            const float* p = Xb + (size_t)i * 64 * IN_F + kt * BK;
            areg[i][0] = *(const float4*)(p);
            areg[i][1] = *(const float4*)(p + 4);
        }
    };
    auto write_A = [&]() {
        unsigned char* ab = smem;
#pragma unroll
        for (int i = 0; i < 4; ++i) {
            uint4 v;
            v.x = pk2(areg[i][0].x, areg[i][0].y);
            v.y = pk2(areg[i][0].z, areg[i][0].w);
            v.z = pk2(areg[i][1].x, areg[i][1].y);
            v.w = pk2(areg[i][1].z, areg[i][1].w);
            *(uint4*)(ab + (i * 64 + arow) * 128 + aphys * 16) = v;
        }
    };

    const int pcol = t & 15;
    const int kd   = t >> 4;
    const int pc7  = pcol & 7;
    const int ob   = kd >> 2;
    const int sub  = (kd & 3) * 4;
    const int* qwb = QW + (size_t)(2 * kd) * PCOLS + P0 + pcol;
    const unsigned int* qzc = (const unsigned int*)QZ + P0 + pcol;
    const float* scol = S + n0 + pcol * 8;

    constexpr int SH[8]  = {0, 16, 4, 20, 8, 24, 12, 28};
    constexpr int JLO[4] = {0, 4, 1, 5};

    h2 spk[8], zpk[8];
    unsigned int zraw_n; float4 sv0, sv1;
    unsigned int raw0, raw1;

    auto load_group = [&](int g) {
        zraw_n = qzc[(size_t)g * PCOLS];
        sv0 = *(const float4*)(scol + (size_t)g * OUT_F);
        sv1 = *(const float4*)(scol + (size_t)g * OUT_F + 4);
    };
    auto compute_group = [&]() {
        const float sf[8] = {sv0.x, sv0.y, sv0.z, sv0.w, sv1.x, sv1.y, sv1.z, sv1.w};
#pragma unroll
        for (int j = 0; j < 8; ++j) {
            float zb = 1024.0f + (float)((zraw_n >> SH[j]) & 15u);
            spk[j] = pkh2(sf[j], sf[j]);
            zpk[j] = pkh2(zb, zb);
        }
    };
    auto load_raws = [&](int kt) {
        const size_t off = (size_t)kt * BK * PCOLS;
        raw0 = (unsigned int)qwb[off];
        raw1 = (unsigned int)qwb[off + PCOLS];
    };
    auto stage_B = [&](int buf) {
        unsigned char* bb = smem + ABYTES_FB + buf * BBYTES;
#pragma unroll
        for (int b = 0; b < 4; ++b) {
            const int jl = JLO[b], jh = jl + 2;
            unsigned int d  = __builtin_amdgcn_perm(raw1, raw0,
                                 (unsigned int)(((4 + b) << 16) | b));
            unsigned int lo = (d & 0x000F000Fu) | 0x64006400u;
            unsigned int hi = ((d >> 4) & 0x000F000Fu) | 0x64006400u;
            h2 wl = (__builtin_bit_cast(h2, lo) - zpk[jl]) * spk[jl];
            h2 wh = (__builtin_bit_cast(h2, hi) - zpk[jh]) * spk[jh];
            const int nl = pcol * 8 + jl, nh = pcol * 8 + jh;
            *(unsigned int*)(bb + nl * 128 + ((ob ^ jl ^ pc7) * 16) + sub) =
                __builtin_bit_cast(unsigned int, wl);
            *(unsigned int*)(bb + nh * 128 + ((ob ^ jh ^ pc7) * 16) + sub) =
                __builtin_bit_cast(unsigned int, wh);
        }
    };

    f32x4 acc[4][4];
#pragma unroll
    for (int mi = 0; mi < 4; ++mi)
#pragma unroll
        for (int ni = 0; ni < 4; ++ni)
            acc[mi][ni] = f32x4{0.f, 0.f, 0.f, 0.f};

    auto compute_tile = [&](int buf) {
        const unsigned char* ab = smem;
        const unsigned char* bb = smem + ABYTES_FB + buf * BBYTES;
#pragma unroll
        for (int ks = 0; ks < 2; ++ks) {
            h8 a[4], bf[4];
#pragma unroll
            for (int mi = 0; mi < 4; ++mi) {
                int off = (wm * 64 + mi * 16 + l15) * 128
                        + (((ks * 4 + l45) ^ l7) * 16);
                a[mi] = *(const h8*)(ab + off);
            }
#pragma unroll
            for (int ni = 0; ni < 4; ++ni) {
                int off = (wn * 64 + ni * 16 + l15) * 128
                        + ((((ks * 4 + l45) ^ l7 ^ l3) ^ (2 * ni)) * 16);
                bf[ni] = *(const h8*)(bb + off);
            }
#pragma unroll
            for (int mi = 0; mi < 4; ++mi)
#pragma unroll
                for (int ni = 0; ni < 4; ++ni)
                    acc[mi][ni] = __builtin_amdgcn_mfma_f32_16x16x32_f16(
                        a[mi], bf[ni], acc[mi][ni], 0, 0, 0);
        }
    };

    load_A(0);
    load_raws(0);
    load_group(0);
    compute_group();
    write_A();
    stage_B(0);
    __syncthreads();

#pragma unroll 2
    for (int kt = 0; kt < NKT; ++kt) {
        const int cur = kt & 1;
        if (kt + 1 < NKT) {
            load_A(kt + 1);
            load_raws(kt + 1);
            if (((kt + 1) & 1) == 0) load_group((kt + 1) >> 1);
        }
        compute_tile(cur);
        if (kt + 1 < NKT) {
            if (((kt + 1) & 1) == 0) compute_group();
            stage_B(cur ^ 1);
        }
        __syncthreads();
        if (kt + 1 < NKT) write_A();
        __syncthreads();
    }

    const int orow0 = m0 + wm * 64 + l45 * 4;
    const int ocol0 = n0 + wn * 64 + l15;
    float bv[4];
#pragma unroll
    for (int ni = 0; ni < 4; ++ni)
        bv[ni] = BIAS[ocol0 + ni * 16];
#pragma unroll
    for (int mi = 0; mi < 4; ++mi)
#pragma unroll
        for (int ni = 0; ni < 4; ++ni)
#pragma unroll
            for (int r = 0; r < 4; ++r) {
                int row = orow0 + mi * 16 + r;
                int col = ocol0 + ni * 16;
                O[(size_t)row * OUT_F + col] = acc[mi][ni][r] + bv[ni];
            }
}

extern "C" void kernel_launch(void* const* d_in, const int* in_sizes, int n_in,
                              void* d_out, int out_size, void* d_ws, size_t ws_size,
                              hipStream_t stream) {
    const float* X  = (const float*)d_in[0];
    const int*   QW = (const int*)d_in[1];
    const int*   QZ = (const int*)d_in[2];
    const float* S  = (const float*)d_in[3];
    const float* Bi = (const float*)d_in[4];
    float*       O  = (float*)d_out;

    if (ws_size >= XSW_BYTES) {
        unsigned short* Xsw = (unsigned short*)d_ws;
        x_convert_kernel<<<dim3(TOKENS * IN_F / 8 / 256), dim3(256), 0, stream>>>(X, Xsw);
        awq_gemm_reg_kernel<<<dim3(8 * NTILES), dim3(512), 0, stream>>>(
            Xsw, QW, QZ, S, Bi, O);
    } else {
        awq_gemm_fb_kernel<<<dim3(8 * NTILES), dim3(512), 0, stream>>>(X, QW, QZ, S, Bi, O);
    }
}

// Round 16
// 238.015 us; speedup vs baseline: 1.9431x; 1.9431x over previous
//
#include <hip/hip_runtime.h>
#include <hip/hip_bf16.h>
#include <stdint.h>

// AWQ GEMM: out[2048,11008](f32) = x[2048,4096](f32,f16-valued) @ dequant4(...) + bias
// Round 16 = round 15 + A-fragment PREFETCH (the r15 regression was zero prefetch
// distance: load_a sat inside compute_tile -> ~300cyc L2 latency exposed before
// each MFMA half, MfmaUtil 27->15.8). Two register fragment sets aA/aB[2][4],
// hand-alternated even/odd (static indexing, rule #20); loads for kt+1 issue at
// top of iter kt -> full-iteration latency cover.
//  K1: X f32->f16 in MFMA-fragment order (unchanged from r15).
//  K2: A global->reg (prefetched), B reg-dequant -> swizzled LDS dbuf, 1 barrier/iter.

constexpr int TOKENS = 2048;
constexpr int IN_F   = 4096;
constexpr int OUT_F  = 11008;
constexpr int PCOLS  = OUT_F / 8;   // 1376
constexpr int BM = 256, BN = 128, BK = 64;
constexpr int NKT    = IN_F / BK;   // 64
constexpr int NTILES = OUT_F / BN;  // 86
constexpr int BBYTES = BN * BK * 2; // 16384 per buffer
constexpr size_t XSW_BYTES = (size_t)TOKENS * IN_F * 2; // 16 MB

typedef _Float16 h2 __attribute__((ext_vector_type(2)));
typedef _Float16 h8 __attribute__((ext_vector_type(8)));
typedef float f32x4  __attribute__((ext_vector_type(4)));

__device__ __forceinline__ h2 pkh2(float a, float b) {
    return __builtin_bit_cast(h2, __builtin_amdgcn_cvt_pkrtz(a, b));
}
__device__ __forceinline__ unsigned int pk2(float a, float b) {
    return __builtin_bit_cast(unsigned int, __builtin_amdgcn_cvt_pkrtz(a, b));
}

// ---------------- K1: convert X into fragment-ordered f16 ----------------
__global__ __launch_bounds__(256)
void x_convert_kernel(const float* __restrict__ X, unsigned short* __restrict__ Xsw)
{
    // g = ((((mt*64 + kt)*2 + ks)*4 + wm)*4 + mi)*64 + lane
    const int g    = blockIdx.x * 256 + threadIdx.x;   // 0 .. 2^20-1
    const int lane = g & 63;
    const int mi   = (g >> 6) & 3;
    const int wm   = (g >> 8) & 3;
    const int ks   = (g >> 10) & 1;
    const int kt   = (g >> 11) & 63;
    const int mt   = g >> 17;
    const int row  = mt * 256 + wm * 64 + mi * 16 + (lane & 15);
    const int kcol = kt * 64 + (ks * 4 + (lane >> 4)) * 8;
    const float* src = X + (size_t)row * IN_F + kcol;
    float4 v0 = *(const float4*)(src);
    float4 v1 = *(const float4*)(src + 4);
    uint4 u;
    u.x = pk2(v0.x, v0.y);
    u.y = pk2(v0.z, v0.w);
    u.z = pk2(v1.x, v1.y);
    u.w = pk2(v1.z, v1.w);
    *(uint4*)(Xsw + (size_t)g * 8) = u;
}

// ---------------- K2: main GEMM (A global->reg prefetched, B via LDS dequant) ----------------
__global__ __launch_bounds__(512, 2)
void awq_gemm_reg_kernel(const unsigned short* __restrict__ Xsw,
                         const int*   __restrict__ QW,
                         const int*   __restrict__ QZ,
                         const float* __restrict__ S,
                         const float* __restrict__ BIAS,
                         float*       __restrict__ O)
{
    // LDS: B buf b at b*16384: [128 cols][128B]; k-octet o of col n at slot o^(n&7)^((n>>3)&7)
    __shared__ alignas(16) unsigned char smem[2 * BBYTES];  // 32 KB

    const int t    = threadIdx.x;
    const int lane = t & 63;
    const int w    = t >> 6;      // 0..7
    const int wm   = w >> 1;      // 0..3 (row block of 64)
    const int wn   = w & 1;       // 0..1 (col block of 64)
    const int l15 = lane & 15, l45 = lane >> 4, l7 = lane & 7, l3 = (lane >> 3) & 1;

    // XCD mapping: XCD x (= bid&7) owns mtile x; sweeps all 86 ntiles. 688 = 8*86.
    const int bid   = blockIdx.x;
    const int mtile = bid & 7;
    const int ntile = bid >> 3;
    const int m0 = mtile * BM;
    const int n0 = ntile * BN;
    const int P0 = n0 >> 3;

    // ---- A fragments: direct global loads from fragment-ordered Xsw ----
    const h8* Afrag = (const h8*)Xsw;   // 16B units
    auto load_afull = [&](h8 (&a)[2][4], int kt) {
#pragma unroll
        for (int ks = 0; ks < 2; ++ks) {
            const size_t base = ((((size_t)mtile * 64 + kt) * 2 + ks) * 4 + wm) * 4;
#pragma unroll
            for (int mi = 0; mi < 4; ++mi)
                a[ks][mi] = Afrag[(base + mi) * 64 + lane];
        }
    };

    // ---- B staging: thread covers packed col pcol = t&15, k-pair 2kd, 2kd+1 (kd = t>>4) ----
    const int pcol = t & 15;
    const int kd   = t >> 4;         // 0..31
    const int pc7  = pcol & 7;
    const int ob   = kd >> 2;        // k-octet
    const int sub  = (kd & 3) * 4;   // byte offset within 16B slot
    const int* qwb = QW + (size_t)(2 * kd) * PCOLS + P0 + pcol;
    const unsigned int* qzc = (const unsigned int*)QZ + P0 + pcol;
    const float* scol = S + n0 + pcol * 8;

    constexpr int SH[8]  = {0, 16, 4, 20, 8, 24, 12, 28}; // shift of logical nibble j
    constexpr int JLO[4] = {0, 4, 1, 5};                  // low-nibble j of byte b

    h2 spk[8], zpk[8];
    unsigned int zraw_n; float4 sv0, sv1;
    unsigned int raw0, raw1;

    auto load_group = [&](int g) {
        zraw_n = qzc[(size_t)g * PCOLS];
        sv0 = *(const float4*)(scol + (size_t)g * OUT_F);
        sv1 = *(const float4*)(scol + (size_t)g * OUT_F + 4);
    };
    auto compute_group = [&]() {
        const float sf[8] = {sv0.x, sv0.y, sv0.z, sv0.w, sv1.x, sv1.y, sv1.z, sv1.w};
#pragma unroll
        for (int j = 0; j < 8; ++j) {
            float zb = 1024.0f + (float)((zraw_n >> SH[j]) & 15u);  // exact in f16
            spk[j] = pkh2(sf[j], sf[j]);
            zpk[j] = pkh2(zb, zb);
        }
    };
    auto load_raws = [&](int kt) {
        const size_t off = (size_t)kt * BK * PCOLS;
        raw0 = (unsigned int)qwb[off];
        raw1 = (unsigned int)qwb[off + PCOLS];
    };
    auto stage_B = [&](int buf) {
        unsigned char* bb = smem + buf * BBYTES;
#pragma unroll
        for (int b = 0; b < 4; ++b) {
            const int jl = JLO[b], jh = jl + 2;
            unsigned int d  = __builtin_amdgcn_perm(raw1, raw0,
                                 (unsigned int)(((4 + b) << 16) | b));
            unsigned int lo = (d & 0x000F000Fu) | 0x64006400u;         // (1024+q), j=jl
            unsigned int hi = ((d >> 4) & 0x000F000Fu) | 0x64006400u;  // j=jh
            h2 wl = (__builtin_bit_cast(h2, lo) - zpk[jl]) * spk[jl];  // exact sub, 1 rounding
            h2 wh = (__builtin_bit_cast(h2, hi) - zpk[jh]) * spk[jh];
            const int nl = pcol * 8 + jl, nh = pcol * 8 + jh;
            *(unsigned int*)(bb + nl * 128 + ((ob ^ jl ^ pc7) * 16) + sub) =
                __builtin_bit_cast(unsigned int, wl);
            *(unsigned int*)(bb + nh * 128 + ((ob ^ jh ^ pc7) * 16) + sub) =
                __builtin_bit_cast(unsigned int, wh);
        }
    };

    f32x4 acc[4][4];
#pragma unroll
    for (int mi = 0; mi < 4; ++mi)
#pragma unroll
        for (int ni = 0; ni < 4; ++ni)
            acc[mi][ni] = f32x4{0.f, 0.f, 0.f, 0.f};

    auto compute_tile = [&](int buf, const h8 (&a)[2][4]) {
        const unsigned char* bb = smem + buf * BBYTES;
#pragma unroll
        for (int ks = 0; ks < 2; ++ks) {
            h8 bf[4];
#pragma unroll
            for (int ni = 0; ni < 4; ++ni) {
                int off = (wn * 64 + ni * 16 + l15) * 128
                        + ((((ks * 4 + l45) ^ l7 ^ l3) ^ (2 * ni)) * 16); // n&7==l7
                bf[ni] = *(const h8*)(bb + off);
            }
#pragma unroll
            for (int mi = 0; mi < 4; ++mi)
#pragma unroll
                for (int ni = 0; ni < 4; ++ni)
                    acc[mi][ni] = __builtin_amdgcn_mfma_f32_16x16x32_f16(
                        a[ks][mi], bf[ni], acc[mi][ni], 0, 0, 0);
        }
    };

    h8 aA[2][4], aB[2][4];

    // ---- prologue: A frags for kt=0 + B tile 0 into buf 0 ----
    load_afull(aA, 0);
    load_raws(0);
    load_group(0);
    compute_group();
    stage_B(0);
    __syncthreads();

    // ---- one K-iteration: consume aC, prefetch into aN ----
    auto K_ITER = [&](int kt, h8 (&aC)[2][4], h8 (&aN)[2][4]) {
        const int cur = kt & 1;
        if (kt + 1 < NKT) {
            load_afull(aN, kt + 1);            // issue-early: full-iter latency cover
            load_raws(kt + 1);
            if (((kt + 1) & 1) == 0) load_group((kt + 1) >> 1);
        }
        compute_tile(cur, aC);
        if (kt + 1 < NKT) {
            if (((kt + 1) & 1) == 0) compute_group();
            stage_B(cur ^ 1);
        }
        __syncthreads();
    };

    // ---- main loop: static even/odd alternation of A reg sets (rule #20) ----
#pragma unroll 1
    for (int kt = 0; kt < NKT; kt += 2) {
        K_ITER(kt,     aA, aB);
        K_ITER(kt + 1, aB, aA);
    }

    // ---- epilogue: bias + f32 store (C/D: col=lane&15, row=(lane>>4)*4+reg) ----
    const int orow0 = m0 + wm * 64 + l45 * 4;
    const int ocol0 = n0 + wn * 64 + l15;
    float bv[4];
#pragma unroll
    for (int ni = 0; ni < 4; ++ni)
        bv[ni] = BIAS[ocol0 + ni * 16];
#pragma unroll
    for (int mi = 0; mi < 4; ++mi)
#pragma unroll
        for (int ni = 0; ni < 4; ++ni)
#pragma unroll
            for (int r = 0; r < 4; ++r) {
                int row = orow0 + mi * 16 + r;
                int col = ocol0 + ni * 16;
                O[(size_t)row * OUT_F + col] = acc[mi][ni][r] + bv[ni];
            }
}

// ---------------- fallback: r12 kernel (ws too small) ----------------
constexpr int ABYTES_FB = BM * BK * 2; // 32768

__global__ __launch_bounds__(512, 2)
void awq_gemm_fb_kernel(const float* __restrict__ X,
                        const int*   __restrict__ QW,
                        const int*   __restrict__ QZ,
                        const float* __restrict__ S,
                        const float* __restrict__ BIAS,
                        float*       __restrict__ O)
{
    __shared__ alignas(16) unsigned char smem[ABYTES_FB + 2 * BBYTES];

    const int t    = threadIdx.x;
    const int lane = t & 63;
    const int w    = t >> 6;
    const int wm   = w >> 1;
    const int wn   = w & 1;
    const int l15 = lane & 15, l45 = lane >> 4, l7 = lane & 7, l3 = (lane >> 3) & 1;

    const int bid   = blockIdx.x;
    const int mtile = bid & 7;
    const int ntile = bid >> 3;
    const int m0 = mtile * BM;
    const int n0 = ntile * BN;
    const int P0 = n0 >> 3;

    const int arow = t >> 3;
    const int aoct = t & 7;
    const int aphys = aoct ^ (arow & 7);
    const float* Xb = X + (size_t)(m0 + arow) * IN_F + aoct * 8;

    float4 areg[4][2];
    auto load_A = [&](int kt) {
#pragma unroll
        for (int i = 0; i < 4; ++i) {
            const float* p = Xb + (size_t)i * 64 * IN_F + kt * BK;
            areg[i][0] = *(const float4*)(p);
            areg[i][1] = *(const float4*)(p + 4);
        }
    };
    auto write_A = [&]() {
        unsigned char* ab = smem;
#pragma unroll
        for (int i = 0; i < 4; ++i) {
            uint4 v;
            v.x = pk2(areg[i][0].x, areg[i][0].y);
            v.y = pk2(areg[i][0].z, areg[i][0].w);
            v.z = pk2(areg[i][1].x, areg[i][1].y);
            v.w = pk2(areg[i][1].z, areg[i][1].w);
            *(uint4*)(ab + (i * 64 + arow) * 128 + aphys * 16) = v;
        }
    };

    const int pcol = t & 15;
    const int kd   = t >> 4;
    const int pc7  = pcol & 7;
    const int ob   = kd >> 2;
    const int sub  = (kd & 3) * 4;
    const int* qwb = QW + (size_t)(2 * kd) * PCOLS + P0 + pcol;
    const unsigned int* qzc = (const unsigned int*)QZ + P0 + pcol;
    const float* scol = S + n0 + pcol * 8;

    constexpr int SH[8]  = {0, 16, 4, 20, 8, 24, 12, 28};
    constexpr int JLO[4] = {0, 4, 1, 5};

    h2 spk[8], zpk[8];
    unsigned int zraw_n; float4 sv0, sv1;
    unsigned int raw0, raw1;

    auto load_group = [&](int g) {
        zraw_n = qzc[(size_t)g * PCOLS];
        sv0 = *(const float4*)(scol + (size_t)g * OUT_F);
        sv1 = *(const float4*)(scol + (size_t)g * OUT_F + 4);
    };
    auto compute_group = [&]() {
        const float sf[8] = {sv0.x, sv0.y, sv0.z, sv0.w, sv1.x, sv1.y, sv1.z, sv1.w};
#pragma unroll
        for (int j = 0; j < 8; ++j) {
            float zb = 1024.0f + (float)((zraw_n >> SH[j]) & 15u);
            spk[j] = pkh2(sf[j], sf[j]);
            zpk[j] = pkh2(zb, zb);
        }
    };
    auto load_raws = [&](int kt) {
        const size_t off = (size_t)kt * BK * PCOLS;
        raw0 = (unsigned int)qwb[off];
        raw1 = (unsigned int)qwb[off + PCOLS];
    };
    auto stage_B = [&](int buf) {
        unsigned char* bb = smem + ABYTES_FB + buf * BBYTES;
#pragma unroll
        for (int b = 0; b < 4; ++b) {
            const int jl = JLO[b], jh = jl + 2;
            unsigned int d  = __builtin_amdgcn_perm(raw1, raw0,
                                 (unsigned int)(((4 + b) << 16) | b));
            unsigned int lo = (d & 0x000F000Fu) | 0x64006400u;
            unsigned int hi = ((d >> 4) & 0x000F000Fu) | 0x64006400u;
            h2 wl = (__builtin_bit_cast(h2, lo) - zpk[jl]) * spk[jl];
            h2 wh = (__builtin_bit_cast(h2, hi) - zpk[jh]) * spk[jh];
            const int nl = pcol * 8 + jl, nh = pcol * 8 + jh;
            *(unsigned int*)(bb + nl * 128 + ((ob ^ jl ^ pc7) * 16) + sub) =
                __builtin_bit_cast(unsigned int, wl);
            *(unsigned int*)(bb + nh * 128 + ((ob ^ jh ^ pc7) * 16) + sub) =
                __builtin_bit_cast(unsigned int, wh);
        }
    };

    f32x4 acc[4][4];
#pragma unroll
    for (int mi = 0; mi < 4; ++mi)
#pragma unroll
        for (int ni = 0; ni < 4; ++ni)
            acc[mi][ni] = f32x4{0.f, 0.f, 0.f, 0.f};

    auto compute_tile = [&](int buf) {
        const unsigned char* ab = smem;
        const unsigned char* bb = smem + ABYTES_FB + buf * BBYTES;
#pragma unroll
        for (int ks = 0; ks < 2; ++ks) {
            h8 a[4], bf[4];
#pragma unroll
            for (int mi = 0; mi < 4; ++mi) {
                int off = (wm * 64 + mi * 16 + l15) * 128
                        + (((ks * 4 + l45) ^ l7) * 16);
                a[mi] = *(const h8*)(ab + off);
            }
#pragma unroll
            for (int ni = 0; ni < 4; ++ni) {
                int off = (wn * 64 + ni * 16 + l15) * 128
                        + ((((ks * 4 + l45) ^ l7 ^ l3) ^ (2 * ni)) * 16);
                bf[ni] = *(const h8*)(bb + off);
            }
#pragma unroll
            for (int mi = 0; mi < 4; ++mi)
#pragma unroll
                for (int ni = 0; ni < 4; ++ni)
                    acc[mi][ni] = __builtin_amdgcn_mfma_f32_16x16x32_f16(
                        a[mi], bf[ni], acc[mi][ni], 0, 0, 0);
        }
    };

    load_A(0);
    load_raws(0);
    load_group(0);
    compute_group();
    write_A();
    stage_B(0);
    __syncthreads();

#pragma unroll 2
    for (int kt = 0; kt < NKT; ++kt) {
        const int cur = kt & 1;
        if (kt + 1 < NKT) {
            load_A(kt + 1);
            load_raws(kt + 1);
            if (((kt + 1) & 1) == 0) load_group((kt + 1) >> 1);
        }
        compute_tile(cur);
        if (kt + 1 < NKT) {
            if (((kt + 1) & 1) == 0) compute_group();
            stage_B(cur ^ 1);
        }
        __syncthreads();
        if (kt + 1 < NKT) write_A();
        __syncthreads();
    }

    const int orow0 = m0 + wm * 64 + l45 * 4;
    const int ocol0 = n0 + wn * 64 + l15;
    float bv[4];
#pragma unroll
    for (int ni = 0; ni < 4; ++ni)
        bv[ni] = BIAS[ocol0 + ni * 16];
#pragma unroll
    for (int mi = 0; mi < 4; ++mi)
#pragma unroll
        for (int ni = 0; ni < 4; ++ni)
#pragma unroll
            for (int r = 0; r < 4; ++r) {
                int row = orow0 + mi * 16 + r;
                int col = ocol0 + ni * 16;
                O[(size_t)row * OUT_F + col] = acc[mi][ni][r] + bv[ni];
            }
}

extern "C" void kernel_launch(void* const* d_in, const int* in_sizes, int n_in,
                              void* d_out, int out_size, void* d_ws, size_t ws_size,
                              hipStream_t stream) {
    const float* X  = (const float*)d_in[0];
    const int*   QW = (const int*)d_in[1];
    const int*   QZ = (const int*)d_in[2];
    const float* S  = (const float*)d_in[3];
    const float* Bi = (const float*)d_in[4];
    float*       O  = (float*)d_out;

    if (ws_size >= XSW_BYTES) {
        unsigned short* Xsw = (unsigned short*)d_ws;
        x_convert_kernel<<<dim3(TOKENS * IN_F / 8 / 256), dim3(256), 0, stream>>>(X, Xsw);
        awq_gemm_reg_kernel<<<dim3(8 * NTILES), dim3(512), 0, stream>>>(
            Xsw, QW, QZ, S, Bi, O);
    } else {
        awq_gemm_fb_kernel<<<dim3(8 * NTILES), dim3(512), 0, stream>>>(X, QW, QZ, S, Bi, O);
    }
}